// Round 5
// baseline (81.300 us; speedup 1.0000x reference)
//
#include <hip/hip_runtime.h>
#include <math.h>

#define NB 64
#define NP 8732
#define NC 81
#define NROWS (NB * NP)            // 558848
#define RPB 32                     // rows per tile
#define TPB 256
#define NTILES (NROWS / RPB)       // 17464 (exact)
#define GRID 2048                  // persistent blocks, ~8 blocks/CU dispatch
#define TILE_FLOATS (RPB * NC)     // 2592
#define TILE_F4 (TILE_FLOATS / 4)  // 648 = 2*256 + 136
#define KPT 35                     // ceil(NP/256); i=34 valid only for tid<28

// ws layout:
//   acc      : double[8]        @ 0   [0]=topK_neg [1]=ce_pos [2]=sl1 [3]=num_pos [4]=ticket
//   partials : double[GRID*3]   @ 64
//   bg       : float[NROWS]     @ BG_OFF
#define PART_OFF 64
#define BG_OFF (PART_OFF + GRID * 3 * 8)   // 49216

__global__ __launch_bounds__(TPB) void mb_rows(
    const float* __restrict__ conf,
    const float* __restrict__ pred,
    const float* __restrict__ gt,
    const int*   __restrict__ labels,
    float* __restrict__ bg,
    double* __restrict__ partials,
    double* __restrict__ acc)
{
    __shared__ __align__(16) float buf[2][TILE_FLOATS];   // 2 x 10368 B
    __shared__ double s_red[4][3];

    const int tid = threadIdx.x;
    if (blockIdx.x == 0 && tid == 0) {
        acc[0] = 0.0; acc[1] = 0.0; acc[2] = 0.0; acc[3] = 0.0; acc[4] = 0.0;
    }

    const int r   = tid >> 3;                 // 0..31 row in tile
    const int h   = tid & 7;                  // eighth-of-row id
    const int off = h * 10;                   // h==7 covers 70..80 (11 floats)

    double ce = 0.0, sl = 0.0, npd = 0.0;

    // ---- DMA stage of one tile into buf[p] (linear lane order) ----
    auto stage = [&](int t, int p) {
        const float4* src4 = (const float4*)(conf + (size_t)t * TILE_FLOATS);
        float4*       dst4 = (float4*)buf[p];
#if __has_builtin(__builtin_amdgcn_global_load_lds)
        __builtin_amdgcn_global_load_lds(
            (const __attribute__((address_space(1))) void*)(src4 + tid),
            (__attribute__((address_space(3))) void*)(dst4 + tid), 16, 0, 0);
        __builtin_amdgcn_global_load_lds(
            (const __attribute__((address_space(1))) void*)(src4 + TPB + tid),
            (__attribute__((address_space(3))) void*)(dst4 + TPB + tid), 16, 0, 0);
#else
        dst4[tid]       = src4[tid];
        dst4[TPB + tid] = src4[TPB + tid];
#endif
        if (tid < TILE_F4 - 2 * TPB)          // 136-float4 tail, plain copy
            dst4[2 * TPB + tid] = src4[2 * TPB + tid];
    };

    int t = blockIdx.x;
    if (t < NTILES) stage(t, 0);
    __syncthreads();

    int p = 0;
    for (; t < NTILES; t += GRID) {
        const int tn = t + GRID;
        if (tn < NTILES) stage(tn, p ^ 1);    // prefetch flies under compute

        // ---- compute tile t from buf[p] ----
        const float* rp = buf[p] + r * NC;
        float v[11];
        #pragma unroll
        for (int j = 0; j < 10; ++j) v[j] = rp[off + j];
        v[10] = (h == 7) ? rp[80] : -__builtin_inff();

        float m = v[0];
        #pragma unroll
        for (int j = 1; j < 11; ++j) m = fmaxf(m, v[j]);
        m = fmaxf(m, __shfl_xor(m, 1));
        m = fmaxf(m, __shfl_xor(m, 2));
        m = fmaxf(m, __shfl_xor(m, 4));

        float s = 0.0f;
        #pragma unroll
        for (int j = 0; j < 11; ++j) s += __expf(v[j] - m);   // exp(-inf)=0
        s += __shfl_xor(s, 1);
        s += __shfl_xor(s, 2);
        s += __shfl_xor(s, 4);

        const float lse = m + __logf(s);

        if (h == 0) {
            const int row = t * RPB + r;
            bg[row] = lse - v[0];             // -log_softmax[...,0]
            const int lbl = labels[row];
            if (lbl > 0) {
                ce  += (double)(lse - rp[lbl]);
                npd += 1.0;
                float4 pv = ((const float4*)pred)[row];
                float4 gv = ((const float4*)gt)[row];
                float d;
                d = fabsf(pv.x - gv.x); sl += (d < 1.f) ? 0.5f * d * d : d - 0.5f;
                d = fabsf(pv.y - gv.y); sl += (d < 1.f) ? 0.5f * d * d : d - 0.5f;
                d = fabsf(pv.z - gv.z); sl += (d < 1.f) ? 0.5f * d * d : d - 0.5f;
                d = fabsf(pv.w - gv.w); sl += (d < 1.f) ? 0.5f * d * d : d - 0.5f;
            }
        }

        __syncthreads();   // reads of buf[p] done; prefetch DMA drained (vmcnt0)
        p ^= 1;
    }

    // ---- block reduce once, at end ----
    #pragma unroll
    for (int o = 32; o; o >>= 1) {
        ce  += __shfl_xor(ce, o);
        sl  += __shfl_xor(sl, o);
        npd += __shfl_xor(npd, o);
    }
    const int wid = tid >> 6, lane = tid & 63;
    if (lane == 0) { s_red[wid][0] = ce; s_red[wid][1] = sl; s_red[wid][2] = npd; }
    __syncthreads();
    if (tid == 0) {
        double a = 0, b = 0, c = 0;
        for (int w = 0; w < 4; ++w) { a += s_red[w][0]; b += s_red[w][1]; c += s_red[w][2]; }
        partials[blockIdx.x * 3 + 0] = a;
        partials[blockIdx.x * 3 + 1] = b;
        partials[blockIdx.x * 3 + 2] = c;
    }
}

// One 256-thread block per batch row: stripe-reduce partials into acc[1..3],
// exact top-K (binary search over register-cached keys), and the last block
// (device-scope ticket) computes the final outputs.
__global__ __launch_bounds__(256) void mb_select(
    const float* __restrict__ bg,
    const int*   __restrict__ labels,
    const double* __restrict__ partials,
    double* __restrict__ acc,
    float* __restrict__ out)
{
    __shared__ unsigned cnt[32];
    __shared__ unsigned s_u[4][3];
    __shared__ double   s_d[4][3];
    __shared__ unsigned s_K, s_lo, s_hi;

    const int b = blockIdx.x, tid = threadIdx.x;
    const int lane = tid & 63, wid = tid >> 6;

    // ---- (a) stripe-reduce partials: j = b + 64*tid, tid<32 (GRID=2048=64*32) ----
    {
        double pce = 0, psl = 0, pnp = 0;
        if (tid < 32) {
            const int j = b + (tid << 6);
            pce = partials[3 * j + 0];
            psl = partials[3 * j + 1];
            pnp = partials[3 * j + 2];
        }
        #pragma unroll
        for (int o = 32; o; o >>= 1) {
            pce += __shfl_xor(pce, o);
            psl += __shfl_xor(psl, o);
            pnp += __shfl_xor(pnp, o);
        }
        if (lane == 0) { s_d[wid][0] = pce; s_d[wid][1] = psl; s_d[wid][2] = pnp; }
    }

    // ---- (b) keys in registers ----
    unsigned k[KPT];
    unsigned np = 0, maxk = 0u, mink = 0xFFFFFFFFu;
    #pragma unroll
    for (int i = 0; i < KPT; ++i) {
        unsigned key = 0u;
        if (i < 34 || tid < 28) {
            const int idx = i * 256 + tid;
            const int   lbl = labels[b * NP + idx];
            const float vv  = bg[b * NP + idx];
            key = (lbl > 0) ? 0u : (__float_as_uint(vv) + 1u);  // bg>=0: order-preserving
            np += (lbl > 0) ? 1u : 0u;
            if (key) { maxk = max(maxk, key); mink = min(mink, key); }
        }
        k[i] = key;
    }
    for (int i = tid; i < 32; i += 256) cnt[i] = 0u;

    #pragma unroll
    for (int o = 32; o; o >>= 1) {
        np   += __shfl_xor(np, o);
        maxk  = max(maxk, __shfl_xor(maxk, o));
        mink  = min(mink, __shfl_xor(mink, o));
    }
    if (lane == 0) { s_u[wid][0] = np; s_u[wid][1] = maxk; s_u[wid][2] = mink; }
    __syncthreads();

    if (tid == 0) {
        double pce = 0, psl = 0, pnp = 0;
        unsigned npt = 0, mx = 0, mn = 0xFFFFFFFFu;
        for (int w = 0; w < 4; ++w) {
            pce += s_d[w][0]; psl += s_d[w][1]; pnp += s_d[w][2];
            npt += s_u[w][0];
            mx = max(mx, s_u[w][1]); mn = min(mn, s_u[w][2]);
        }
        atomicAdd(&acc[1], pce);
        atomicAdd(&acc[2], psl);
        atomicAdd(&acc[3], pnp);
        unsigned K = 3u * npt;
        const unsigned nneg = NP - npt;
        if (K > nneg) K = nneg;
        s_K = K; s_lo = mn; s_hi = mx;
    }
    __syncthreads();

    const unsigned K = s_K;
    if (K > 0) {
        // smallest x with count(key > x) < K  ->  key of K-th largest
        unsigned lo = s_lo, hi = s_hi;
        int it = 0;
        while (lo < hi) {
            const unsigned mid = lo + ((hi - lo) >> 1);
            unsigned c = 0;
            #pragma unroll
            for (int i = 0; i < KPT; ++i) c += (k[i] > mid) ? 1u : 0u;
            #pragma unroll
            for (int o = 32; o; o >>= 1) c += __shfl_xor(c, o);
            if (lane == 0) atomicAdd(&cnt[it], c);
            __syncthreads();
            if (cnt[it] < K) hi = mid; else lo = mid + 1;
            ++it;
        }
        const unsigned V = lo;            // exact key of K-th largest (>=1)

        double ssum = 0.0; unsigned cgt = 0;
        #pragma unroll
        for (int i = 0; i < KPT; ++i) {
            const unsigned kk = k[i];
            if (kk > V) { ssum += (double)__uint_as_float(kk - 1u); cgt++; }
        }
        #pragma unroll
        for (int o = 32; o; o >>= 1) { ssum += __shfl_xor(ssum, o); cgt += __shfl_xor(cgt, o); }
        if (lane == 0) { s_d[wid][0] = ssum; s_u[wid][0] = cgt; }
        __syncthreads();
        if (tid == 0) {
            double tot = s_d[0][0] + s_d[1][0] + s_d[2][0] + s_d[3][0];
            const unsigned cg = s_u[0][0] + s_u[1][0] + s_u[2][0] + s_u[3][0];
            tot += (double)(K - cg) * (double)__uint_as_float(V - 1u);  // ties at V
            atomicAdd(&acc[0], tot);
        }
    }

    // ---- fused finalization: last block through the ticket writes out ----
    if (tid == 0) {
        __threadfence();
        const unsigned done = atomicAdd((unsigned*)(acc + 4), 1u);
        if (done == NB - 1) {
            __threadfence();
            const double topk = atomicAdd(&acc[0], 0.0);   // device-scope reads
            const double pce  = atomicAdd(&acc[1], 0.0);
            const double psl  = atomicAdd(&acc[2], 0.0);
            const double npd  = atomicAdd(&acc[3], 0.0);
            out[0] = (float)(psl / npd);            // smooth_l1 / num_pos
            out[1] = (float)((pce + topk) / npd);   // classification / num_pos
        }
    }
}

extern "C" void kernel_launch(void* const* d_in, const int* in_sizes, int n_in,
                              void* d_out, int out_size, void* d_ws, size_t ws_size,
                              hipStream_t stream)
{
    const float* conf   = (const float*)d_in[0];
    const float* pred   = (const float*)d_in[1];
    const int*   labels = (const int*)d_in[2];
    const float* gt     = (const float*)d_in[3];
    float* out = (float*)d_out;

    double* acc      = (double*)d_ws;
    double* partials = (double*)((char*)d_ws + PART_OFF);
    float*  bg       = (float*)((char*)d_ws + BG_OFF);

    mb_rows<<<GRID, TPB, 0, stream>>>(conf, pred, gt, labels, bg, partials, acc);
    mb_select<<<NB, 256, 0, stream>>>(bg, labels, partials, acc, out);
}

// Round 6
// 74.522 us; speedup vs baseline: 1.0910x; 1.0910x over previous
//
#include <hip/hip_runtime.h>
#include <math.h>

#define NB 64
#define NP 8732
#define NC 81
#define NROWS (NB * NP)            // 558848
#define RPB 32                     // rows per block-tile (8 per wave)
#define TPB 256
#define NTILES (NROWS / RPB)       // 17464 (exact)
#define GRID 1792                  // == resident capacity: 7 blocks/CU x 256 CU
#define SLICE_FLOATS (8 * NC)      // 648 floats = 2592 B per wave-slice
#define SLICE_F4 (SLICE_FLOATS / 4)// 162 = 64 + 64 + 34
#define KPT 35                     // ceil(NP/256); i=34 valid only for tid<28

// ws layout:
//   acc      : double[8]        @ 0   [0]=topK_neg [1]=ce_pos [2]=sl1 [3]=num_pos [4]=ticket
//   partials : double[GRID*3]   @ 64
//   bg       : float[NROWS]     @ BG_OFF
#define PART_OFF 64
#define BG_OFF (PART_OFF + GRID * 3 * 8)   // 43072 (16B aligned)

__global__ __launch_bounds__(TPB) void mb_rows(
    const float* __restrict__ conf,
    const float* __restrict__ pred,
    const float* __restrict__ gt,
    const int*   __restrict__ labels,
    float* __restrict__ bg,
    double* __restrict__ partials,
    double* __restrict__ acc)
{
    __shared__ __align__(16) float lds[4][2][SLICE_FLOATS];  // 20736 B
    __shared__ double s_red[4][3];

    const int tid  = threadIdx.x;
    const int w    = tid >> 6;
    const int lane = tid & 63;

    if (blockIdx.x == 0 && tid == 0) {
        acc[0] = 0.0; acc[1] = 0.0; acc[2] = 0.0; acc[3] = 0.0; acc[4] = 0.0;
    }

    const int r   = lane >> 3;                // 0..7 : row within wave slice
    const int h   = lane & 7;                 // eighth-of-row
    const int off = h * 10;                   // h==7 covers 70..80

    double ce = 0.0, sl = 0.0, npd = 0.0;

    // wave-private DMA of one 8-row slice into lds[w][p] (linear lane order)
    auto stage = [&](int t, int p) {
        const float4* s4 = (const float4*)(conf + (size_t)t * (RPB * NC) + w * SLICE_FLOATS);
        float4*       d4 = (float4*)lds[w][p];
#if __has_builtin(__builtin_amdgcn_global_load_lds)
        __builtin_amdgcn_global_load_lds(
            (const __attribute__((address_space(1))) void*)(s4 + lane),
            (__attribute__((address_space(3))) void*)(d4 + lane), 16, 0, 0);
        __builtin_amdgcn_global_load_lds(
            (const __attribute__((address_space(1))) void*)(s4 + 64 + lane),
            (__attribute__((address_space(3))) void*)(d4 + 64 + lane), 16, 0, 0);
        if (lane < SLICE_F4 - 128)
            __builtin_amdgcn_global_load_lds(
                (const __attribute__((address_space(1))) void*)(s4 + 128 + lane),
                (__attribute__((address_space(3))) void*)(d4 + 128 + lane), 16, 0, 0);
#else
        d4[lane]      = s4[lane];
        d4[64 + lane] = s4[64 + lane];
        if (lane < SLICE_F4 - 128) d4[128 + lane] = s4[128 + lane];
#endif
    };

    int t = blockIdx.x;
    stage(t, 0);                               // GRID < NTILES: always valid

    int p = 0;
    for (; t < NTILES; t += GRID) {
        // wave-private completion wait for OUR slice DMA (no __syncthreads)
        asm volatile("s_waitcnt vmcnt(0)" ::: "memory");

        const float* rp = &lds[w][p][r * NC];
        float v[11];
        #pragma unroll
        for (int j = 0; j < 10; ++j) v[j] = rp[off + j];
        v[10] = (h == 7) ? rp[80] : -__builtin_inff();

        // prefetch the next slice into the other buffer; flies under compute
        const int tn = t + GRID;
        if (tn < NTILES) stage(tn, p ^ 1);

        float m = v[0];
        #pragma unroll
        for (int j = 1; j < 11; ++j) m = fmaxf(m, v[j]);
        m = fmaxf(m, __shfl_xor(m, 1));
        m = fmaxf(m, __shfl_xor(m, 2));
        m = fmaxf(m, __shfl_xor(m, 4));

        float s = 0.0f;
        #pragma unroll
        for (int j = 0; j < 11; ++j) s += __expf(v[j] - m);   // exp(-inf)=0
        s += __shfl_xor(s, 1);
        s += __shfl_xor(s, 2);
        s += __shfl_xor(s, 4);

        const float lse = m + __logf(s);

        if (h == 0) {
            const int row = t * RPB + w * 8 + r;
            bg[row] = lse - v[0];              // -log_softmax[...,0]
            const int lbl = labels[row];
            if (lbl > 0) {
                ce  += (double)(lse - rp[lbl]);
                npd += 1.0;
                float4 pv = ((const float4*)pred)[row];
                float4 gv = ((const float4*)gt)[row];
                float d;
                d = fabsf(pv.x - gv.x); sl += (d < 1.f) ? 0.5f * d * d : d - 0.5f;
                d = fabsf(pv.y - gv.y); sl += (d < 1.f) ? 0.5f * d * d : d - 0.5f;
                d = fabsf(pv.z - gv.z); sl += (d < 1.f) ? 0.5f * d * d : d - 0.5f;
                d = fabsf(pv.w - gv.w); sl += (d < 1.f) ? 0.5f * d * d : d - 0.5f;
            }
        }
        p ^= 1;
    }

    // ---- block reduce once, at end (single barrier in the kernel) ----
    #pragma unroll
    for (int o = 32; o; o >>= 1) {
        ce  += __shfl_xor(ce, o);
        sl  += __shfl_xor(sl, o);
        npd += __shfl_xor(npd, o);
    }
    if (lane == 0) { s_red[w][0] = ce; s_red[w][1] = sl; s_red[w][2] = npd; }
    __syncthreads();
    if (tid == 0) {
        double a = 0, b = 0, c = 0;
        for (int q = 0; q < 4; ++q) { a += s_red[q][0]; b += s_red[q][1]; c += s_red[q][2]; }
        partials[blockIdx.x * 3 + 0] = a;
        partials[blockIdx.x * 3 + 1] = b;
        partials[blockIdx.x * 3 + 2] = c;
    }
}

// One 256-thread block per batch row: stripe-reduce partials into acc[1..3],
// exact top-K (binary search over register-cached keys), last block through
// the device-scope ticket writes the outputs.
__global__ __launch_bounds__(256) void mb_select(
    const float* __restrict__ bg,
    const int*   __restrict__ labels,
    const double* __restrict__ partials,
    double* __restrict__ acc,
    float* __restrict__ out)
{
    __shared__ unsigned cnt[32];
    __shared__ unsigned s_u[4][3];
    __shared__ double   s_d[4][3];
    __shared__ unsigned s_K, s_lo, s_hi;

    const int b = blockIdx.x, tid = threadIdx.x;
    const int lane = tid & 63, wid = tid >> 6;

    // ---- (a) stripe-reduce partials: j = b + 64*tid, tid<28 (GRID=1792=64*28) ----
    {
        double pce = 0, psl = 0, pnp = 0;
        if (tid < 28) {
            const int j = b + (tid << 6);
            pce = partials[3 * j + 0];
            psl = partials[3 * j + 1];
            pnp = partials[3 * j + 2];
        }
        #pragma unroll
        for (int o = 32; o; o >>= 1) {
            pce += __shfl_xor(pce, o);
            psl += __shfl_xor(psl, o);
            pnp += __shfl_xor(pnp, o);
        }
        if (lane == 0) { s_d[wid][0] = pce; s_d[wid][1] = psl; s_d[wid][2] = pnp; }
    }

    // ---- (b) keys in registers ----
    unsigned k[KPT];
    unsigned np = 0, maxk = 0u, mink = 0xFFFFFFFFu;
    #pragma unroll
    for (int i = 0; i < KPT; ++i) {
        unsigned key = 0u;
        if (i < 34 || tid < 28) {
            const int idx = i * 256 + tid;
            const int   lbl = labels[b * NP + idx];
            const float vv  = bg[b * NP + idx];
            key = (lbl > 0) ? 0u : (__float_as_uint(vv) + 1u);  // bg>=0: order-preserving
            np += (lbl > 0) ? 1u : 0u;
            if (key) { maxk = max(maxk, key); mink = min(mink, key); }
        }
        k[i] = key;
    }
    for (int i = tid; i < 32; i += 256) cnt[i] = 0u;

    #pragma unroll
    for (int o = 32; o; o >>= 1) {
        np   += __shfl_xor(np, o);
        maxk  = max(maxk, __shfl_xor(maxk, o));
        mink  = min(mink, __shfl_xor(mink, o));
    }
    if (lane == 0) { s_u[wid][0] = np; s_u[wid][1] = maxk; s_u[wid][2] = mink; }
    __syncthreads();

    if (tid == 0) {
        double pce = 0, psl = 0, pnp = 0;
        unsigned npt = 0, mx = 0, mn = 0xFFFFFFFFu;
        for (int q = 0; q < 4; ++q) {
            pce += s_d[q][0]; psl += s_d[q][1]; pnp += s_d[q][2];
            npt += s_u[q][0];
            mx = max(mx, s_u[q][1]); mn = min(mn, s_u[q][2]);
        }
        atomicAdd(&acc[1], pce);
        atomicAdd(&acc[2], psl);
        atomicAdd(&acc[3], pnp);
        unsigned K = 3u * npt;
        const unsigned nneg = NP - npt;
        if (K > nneg) K = nneg;
        s_K = K; s_lo = mn; s_hi = mx;
    }
    __syncthreads();

    const unsigned K = s_K;
    if (K > 0) {
        // smallest x with count(key > x) < K  ->  key of K-th largest
        unsigned lo = s_lo, hi = s_hi;
        int it = 0;
        while (lo < hi) {
            const unsigned mid = lo + ((hi - lo) >> 1);
            unsigned c = 0;
            #pragma unroll
            for (int i = 0; i < KPT; ++i) c += (k[i] > mid) ? 1u : 0u;
            #pragma unroll
            for (int o = 32; o; o >>= 1) c += __shfl_xor(c, o);
            if (lane == 0) atomicAdd(&cnt[it], c);
            __syncthreads();
            if (cnt[it] < K) hi = mid; else lo = mid + 1;
            ++it;
        }
        const unsigned V = lo;            // exact key of K-th largest (>=1)

        double ssum = 0.0; unsigned cgt = 0;
        #pragma unroll
        for (int i = 0; i < KPT; ++i) {
            const unsigned kk = k[i];
            if (kk > V) { ssum += (double)__uint_as_float(kk - 1u); cgt++; }
        }
        #pragma unroll
        for (int o = 32; o; o >>= 1) { ssum += __shfl_xor(ssum, o); cgt += __shfl_xor(cgt, o); }
        if (lane == 0) { s_d[wid][0] = ssum; s_u[wid][0] = cgt; }
        __syncthreads();
        if (tid == 0) {
            double tot = s_d[0][0] + s_d[1][0] + s_d[2][0] + s_d[3][0];
            const unsigned cg = s_u[0][0] + s_u[1][0] + s_u[2][0] + s_u[3][0];
            tot += (double)(K - cg) * (double)__uint_as_float(V - 1u);  // ties at V
            atomicAdd(&acc[0], tot);
        }
    }

    // ---- fused finalization: last block through the ticket writes out ----
    if (tid == 0) {
        __threadfence();
        const unsigned done = atomicAdd((unsigned*)(acc + 4), 1u);
        if (done == NB - 1) {
            __threadfence();
            const double topk = atomicAdd(&acc[0], 0.0);   // device-scope reads
            const double pce  = atomicAdd(&acc[1], 0.0);
            const double psl  = atomicAdd(&acc[2], 0.0);
            const double npd  = atomicAdd(&acc[3], 0.0);
            out[0] = (float)(psl / npd);            // smooth_l1 / num_pos
            out[1] = (float)((pce + topk) / npd);   // classification / num_pos
        }
    }
}

extern "C" void kernel_launch(void* const* d_in, const int* in_sizes, int n_in,
                              void* d_out, int out_size, void* d_ws, size_t ws_size,
                              hipStream_t stream)
{
    const float* conf   = (const float*)d_in[0];
    const float* pred   = (const float*)d_in[1];
    const int*   labels = (const int*)d_in[2];
    const float* gt     = (const float*)d_in[3];
    float* out = (float*)d_out;

    double* acc      = (double*)d_ws;
    double* partials = (double*)((char*)d_ws + PART_OFF);
    float*  bg       = (float*)((char*)d_ws + BG_OFF);

    mb_rows<<<GRID, TPB, 0, stream>>>(conf, pred, gt, labels, bg, partials, acc);
    mb_select<<<NB, 256, 0, stream>>>(bg, labels, partials, acc, out);
}